// Round 7
// baseline (215.561 us; speedup 1.0000x reference)
//
#include <hip/hip_runtime.h>

// Reference collapses: softmax over a size-1 key axis == 1.0, so
// out[bn,t,:] = padded[bn,t,:] + (masked_mean_t(padded[bn]) @ Wv + bv).
// q/k/rope/positions/sum_token are dead code.
//
// R11: many-small-blocks, 2 dispatches.  Unified post-mortem of R5-R10:
// every fused variant (70-84us, 2.2-2.6 TB/s) was duty-cycle-limited --
// 256-512 heavyweight lockstep blocks = 1-2 blocks/CU, so during each
// block's reduce/matvec/barrier segments the CU demands ~0 GB/s and no
// other block is resident to backfill.  The harness's own fill kernel
// proves the chip does 6.7 TB/s at 9% occupancy with ~100k tiny blocks:
// BW saturation = deep queue of independent blocks, nothing else.
//   D1 (2048 blocks): quarter-bn (32-row) masked partial colsums -> ws.
//      Pure 100 MB streaming read, 8 blocks/CU backfill.
//   D2 (1024 blocks): block = (bn, col-half).  Short prologue: reduce 4
//      partials -> summary -> matvec for its 192 cols (Wv slice 288 KB,
//      L2-hot, 295 MB chip-wide L2 traffic).  Then stream out = padded+v
//      for its 128x192 slab; padded is L3-hot from D1.  nt stores.
// Dispatch gap under graph capture ~2-4us (R0's 3-dispatch total already
// beat nothing-else; gap is cheap).  Prediction: both dispatches
// >=4.5 TB/s, D1 ~20us, D2 ~30us.

#define DM 384
#define TT 128
#define C4 96          // DM / 4
#define BN_TOT 512

typedef float f32x4 __attribute__((ext_vector_type(4)));

__device__ __forceinline__ void nt_store4(float4* p, const float4 v) {
    __builtin_nontemporal_store(*(const f32x4*)&v, (f32x4*)p);
}

// ---------------- D1: quarter-bn masked partial colsums ----------------
// block b: bn = b>>2, q = b&3 (rows q*32 .. q*32+31). 384 threads:
// c = t%96 (float4 col), rr = t/96 (0..3); 8 rows/thread.
__global__ __launch_bounds__(384) void k_partial(
    const float* __restrict__ padded,
    const int*   __restrict__ masks,
    float*       __restrict__ ws_part,   // (BN, 4, DM)
    float*       __restrict__ ws_cnt)    // (BN, 4)
{
    const int b  = blockIdx.x;
    const int bn = b >> 2;
    const int q  = b & 3;
    const int t  = threadIdx.x;
    const int c  = t % C4;
    const int rr = t / C4;               // 0..3

    __shared__ float  w_sh[32];
    __shared__ float4 part[4][C4];       // 6 KB

    if (t < 32) w_sh[t] = (float)masks[bn * TT + q * 32 + t];
    __syncthreads();

    const float4* __restrict__ p4 =
        (const float4*)padded + (size_t)bn * TT * C4 + (size_t)q * 32 * C4;

    float4 acc = make_float4(0.f, 0.f, 0.f, 0.f);
    #pragma unroll
    for (int j = 0; j < 8; ++j) {
        const int   r = rr + 4 * j;      // 0..31 within quarter
        const float w = w_sh[r];
        const float4 x = p4[r * C4 + c];
        acc.x += x.x * w; acc.y += x.y * w; acc.z += x.z * w; acc.w += x.w * w;
    }
    part[rr][c] = acc;
    __syncthreads();

    if (t < C4) {
        const float4 a0 = part[0][t], a1 = part[1][t];
        const float4 a2 = part[2][t], a3 = part[3][t];
        float4 s;
        s.x = (a0.x + a1.x) + (a2.x + a3.x);
        s.y = (a0.y + a1.y) + (a2.y + a3.y);
        s.z = (a0.z + a1.z) + (a2.z + a3.z);
        s.w = (a0.w + a1.w) + (a2.w + a3.w);
        ((float4*)(ws_part + ((size_t)bn * 4 + q) * DM))[t] = s;
    } else if (t == C4) {
        float s0 = 0.f, s1 = 0.f, s2 = 0.f, s3 = 0.f;
        #pragma unroll
        for (int i = 0; i < 8; ++i) {
            s0 += w_sh[i];      s1 += w_sh[8 + i];
            s2 += w_sh[16 + i]; s3 += w_sh[24 + i];
        }
        ws_cnt[bn * 4 + q] = (s0 + s1) + (s2 + s3);
    }
}

// ---------------- D2: finalize + matvec + streaming add ----------------
// block b: bn = b>>1, h = b&1 (col-half: float4 cols h*48 .. h*48+47).
// 384 threads: c4 = t%48 (col4 within half), eg/rr = t/48 (0..7).
__global__ __launch_bounds__(384) void k_final_add(
    const float* __restrict__ padded,
    const float* __restrict__ ws_part,   // (BN, 4, DM)
    const float* __restrict__ ws_cnt,    // (BN, 4)
    const float* __restrict__ Wv,
    const float* __restrict__ bv,
    float*       __restrict__ out)
{
    const int b  = blockIdx.x;
    const int bn = b >> 1;
    const int h  = b & 1;
    const int t  = threadIdx.x;
    const int c4 = t % 48;
    const int g8 = t / 48;               // 0..7

    __shared__ float  summ[DM];          // 1.5 KB
    __shared__ float4 mpart[8][48];      // 6 KB
    __shared__ float4 v_sh[48];          // 768 B

    // ---- prologue 1: summary = (sum of 4 partials) / denom ----
    {
        const float* __restrict__ pp = ws_part + (size_t)bn * 4 * DM;
        const float  s = (pp[t] + pp[DM + t]) + (pp[2 * DM + t] + pp[3 * DM + t]);
        const float* __restrict__ cc = ws_cnt + bn * 4;
        const float  cnt = (cc[0] + cc[1]) + (cc[2] + cc[3]);
        summ[t] = s * (1.0f / fmaxf(cnt, 1e-6f));
    }
    __syncthreads();

    // ---- prologue 2: matvec for this half's 48 col4 ----
    // thread (c4, eg): e in [eg*48, eg*48+48); Wv slice 288 KB, L2-hot.
    {
        float4 a = make_float4(0.f, 0.f, 0.f, 0.f);
        const float4* __restrict__ wv4 = (const float4*)Wv;
        #pragma unroll 6
        for (int j = 0; j < 48; ++j) {
            const int   e = g8 * 48 + j;
            const float s = summ[e];                        // LDS broadcast
            const float4 w = wv4[(size_t)e * C4 + h * 48 + c4];
            a.x += s * w.x; a.y += s * w.y; a.z += s * w.z; a.w += s * w.w;
        }
        mpart[g8][c4] = a;
    }
    __syncthreads();

    if (t < 48) {
        float4 v = ((const float4*)bv)[h * 48 + t];
        #pragma unroll
        for (int g = 0; g < 8; ++g) {
            const float4 p = mpart[g][t];
            v.x += p.x; v.y += p.y; v.z += p.z; v.w += p.w;
        }
        v_sh[t] = v;
    }
    __syncthreads();

    // ---- stream: out = padded + v over 128 rows x this col-half ----
    // thread (c4, rr): rows rr+8j; per row the half is 768 B contiguous.
    const float4* __restrict__ p4 = (const float4*)padded + (size_t)bn * TT * C4;
    float4*       __restrict__ o4 = (float4*)out + (size_t)bn * TT * C4;
    const float4 v = v_sh[c4];
    #pragma unroll
    for (int j = 0; j < 16; ++j) {
        const int    r   = g8 + 8 * j;
        const size_t idx = (size_t)r * C4 + h * 48 + c4;
        float4 x = p4[idx];
        x.x += v.x; x.y += v.y; x.z += v.z; x.w += v.w;
        nt_store4(&o4[idx], x);
    }
}

extern "C" void kernel_launch(void* const* d_in, const int* in_sizes, int n_in,
                              void* d_out, int out_size, void* d_ws, size_t ws_size,
                              hipStream_t stream) {
    const float* padded = (const float*)d_in[0];
    // d_in[1] sum_token, d_in[2] positions_3d, d_in[3..6] Wq/bq/Wk/bk: dead
    const float* Wv     = (const float*)d_in[7];
    const float* bv     = (const float*)d_in[8];
    const int*   masks  = (const int*)d_in[9];
    float* out = (float*)d_out;

    float* ws_part = (float*)d_ws;                       // 512*4*384 floats
    float* ws_cnt  = ws_part + (size_t)BN_TOT * 4 * DM;  // 512*4 floats

    k_partial<<<BN_TOT * 4, 384, 0, stream>>>(padded, masks, ws_part, ws_cnt);
    k_final_add<<<BN_TOT * 2, 384, 0, stream>>>(padded, ws_part, ws_cnt,
                                                Wv, bv, out);
}